// Round 8
// baseline (740.660 us; speedup 1.0000x reference)
//
#include <hip/hip_runtime.h>
#include <cstdint>
#include <cstddef>

#define T_STEPS 64
#define BATCH 512
#define IN_F 784
#define NKT 25          // k-tiles of 32 (784 padded to 800)
#define HID 2048
#define OUT_F 10

#define DEC_V 0.9f
#define DEC_I 0.8f
#define DT_V 0.1f
#define V_TH 0.5f

typedef __attribute__((ext_vector_type(8))) _Float16 f16x8;
typedef __attribute__((ext_vector_type(4))) float f32x4;

__device__ __forceinline__ void load_lds16h(const _Float16* g, _Float16* l) {
  __builtin_amdgcn_global_load_lds(
      (const __attribute__((address_space(1))) void*)g,
      (__attribute__((address_space(3))) void*)l, 16, 0, 0);
}

// ---------------------------------------------------------------------------
// Split fp32 [nrows,784] into f16 hi/lo in FRAGMENT-TILE order (R7-verified):
// tile (mt,kt) = 512 halves; lane l holds row (l&15), k-slice (l>>4)*8..+8.
// ---------------------------------------------------------------------------
__global__ __launch_bounds__(256)
void split_frag(const float* __restrict__ src, _Float16* __restrict__ hiT,
                _Float16* __restrict__ loT) {
  __shared__ float xr[16][804];
  const int mt = blockIdx.x;
  for (int i = threadIdx.x; i < 16 * IN_F; i += 256) {
    const int r = i / IN_F, c = i - r * IN_F;
    xr[r][c] = src[(size_t)(mt * 16 + r) * IN_F + c];
  }
  for (int i = threadIdx.x; i < 16 * 16; i += 256)
    xr[i >> 4][IN_F + (i & 15)] = 0.0f;
  __syncthreads();

  const int l = threadIdx.x & 63;
  const int g = threadIdx.x >> 6;
  const int r = l & 15, q = l >> 4;
  for (int kt = g; kt < NKT; kt += 4) {
    const float* s = &xr[r][kt * 32 + q * 8];
    f16x8 h, lo;
#pragma unroll
    for (int j = 0; j < 8; ++j) {
      const float v = s[j];
      const _Float16 hh = (_Float16)v;       // RTN
      h[j] = hh;
      lo[j] = (_Float16)(v - (float)hh);
    }
    const size_t off = ((size_t)mt * NKT + kt) * 512 + l * 8;
    *(f16x8*)&hiT[off] = h;
    *(f16x8*)&loT[off] = lo;
  }
}

// ---------------------------------------------------------------------------
// MFMA GEMM (R7 structure, 3 blocks/CU): C[m,n] = sum_k A[m,k]*W[n,k] via
// 3x f16-split products. Block 128(M) x 256(N), wave tile 64x128 (4x8 of
// 16x16x32): 96 MFMA : 24 conflict-free b128 frag reads per ktile.
// ---------------------------------------------------------------------------
__global__ __launch_bounds__(256, 3)
void gemm_fc1(const _Float16* __restrict__ AhT, const _Float16* __restrict__ AlT,
              const _Float16* __restrict__ WhT, const _Float16* __restrict__ WlT,
              float* __restrict__ C) {
  __shared__ _Float16 __attribute__((aligned(16))) sAh[8 * 512];
  __shared__ _Float16 __attribute__((aligned(16))) sAl[8 * 512];
  __shared__ _Float16 __attribute__((aligned(16))) sWh[16 * 512];
  __shared__ _Float16 __attribute__((aligned(16))) sWl[16 * 512];

  const int tid = threadIdx.x;
  const int lane = tid & 63;
  const int wv = tid >> 6;
  const int bmT = blockIdx.y * 8;
  const int bnT = blockIdx.x * 16;

  const int wrT = (wv >> 1) * 4;
  const int wcT = (wv & 1) * 8;
  const int col = lane & 15;
  const int quad = lane >> 4;

  f32x4 acc[4][8] = {};

  for (int kt = 0; kt < NKT; ++kt) {
    __syncthreads();
#pragma unroll
    for (int j = 0; j < 2; ++j) {
      const int t = wv * 2 + j;
      const size_t go = ((size_t)(bmT + t) * NKT + kt) * 512 + lane * 8;
      load_lds16h(AhT + go, sAh + t * 512);
      load_lds16h(AlT + go, sAl + t * 512);
    }
#pragma unroll
    for (int j = 0; j < 4; ++j) {
      const int t = wv * 4 + j;
      const size_t go = ((size_t)(bnT + t) * NKT + kt) * 512 + lane * 8;
      load_lds16h(WhT + go, sWh + t * 512);
      load_lds16h(WlT + go, sWl + t * 512);
    }
    __syncthreads();

    f16x8 fah[4], fal[4];
#pragma unroll
    for (int i = 0; i < 4; ++i) {
      fah[i] = *(const f16x8*)&sAh[(wrT + i) * 512 + lane * 8];
      fal[i] = *(const f16x8*)&sAl[(wrT + i) * 512 + lane * 8];
    }
#pragma unroll
    for (int ni = 0; ni < 8; ++ni) {
      const f16x8 fwh = *(const f16x8*)&sWh[(wcT + ni) * 512 + lane * 8];
      const f16x8 fwl = *(const f16x8*)&sWl[(wcT + ni) * 512 + lane * 8];
#pragma unroll
      for (int mi = 0; mi < 4; ++mi) {
        acc[mi][ni] = __builtin_amdgcn_mfma_f32_16x16x32_f16(fah[mi], fwh, acc[mi][ni], 0, 0, 0);
        acc[mi][ni] = __builtin_amdgcn_mfma_f32_16x16x32_f16(fah[mi], fwl, acc[mi][ni], 0, 0, 0);
        acc[mi][ni] = __builtin_amdgcn_mfma_f32_16x16x32_f16(fal[mi], fwh, acc[mi][ni], 0, 0, 0);
      }
    }
  }

  const int rowb = blockIdx.y * 128 + (wv >> 1) * 64;
  const int colb = blockIdx.x * 256 + (wv & 1) * 128;
#pragma unroll
  for (int mi = 0; mi < 4; ++mi)
#pragma unroll
    for (int ni = 0; ni < 8; ++ni)
#pragma unroll
      for (int r = 0; r < 4; ++r)
        C[(size_t)(rowb + mi * 16 + quad * 4 + r) * HID + colb + ni * 16 + col] =
            acc[mi][ni][r];
}

// ---------------------------------------------------------------------------
// Fused LIF scan + output projection; epilogue atomically accumulates the
// 8 h-chunk contributions into outcur[t][b][o] (order-dependent rounding
// ~1 ulp — well inside the absmax margin).
// ---------------------------------------------------------------------------
__global__ __launch_bounds__(256)
void lif_out(const float* __restrict__ cur, const float* __restrict__ wo,
             float* __restrict__ v1, float* __restrict__ i1,
             float* __restrict__ outcur, int tc, int t0) {
  __shared__ _Float16 zL[T_STEPS][264];
  __shared__ _Float16 wT[16][264];

  const int tid = threadIdx.x;
  const int hc = blockIdx.x;
  const int b = blockIdx.y;
  const int hb = hc * 256;

  for (int i = tid; i < 16 * 256; i += 256) {
    const int n = i >> 8, k = i & 255;
    wT[n][k] = (n < OUT_F) ? (_Float16)wo[(size_t)n * HID + hb + k] : (_Float16)0.f;
  }

  const int sidx = b * HID + hb + tid;
  float v = v1[sidx];
  float ci = i1[sidx];
#pragma unroll 4
  for (int t = 0; t < tc; ++t) {
    const float c = cur[(size_t)t * (BATCH * HID) + sidx];
    const float vd = DEC_V * v + DT_V * ci;
    const float z = (vd > V_TH) ? 1.0f : 0.0f;
    v = (1.0f - z) * vd;
    ci = DEC_I * ci + c;
    zL[t][tid] = (_Float16)z;
  }
  v1[sidx] = v;
  i1[sidx] = ci;
  __syncthreads();

  const int wv = tid >> 6;
  const int lane = tid & 63;
  const int col = lane & 15;
  const int quad = lane >> 4;
  f32x4 acc = {};
  const _Float16* za = &zL[wv * 16 + col][0];
  const _Float16* wb = &wT[col][0];
#pragma unroll
  for (int ks = 0; ks < 8; ++ks) {
    f16x8 a = *(const f16x8*)(za + ks * 32 + quad * 8);
    f16x8 bb = *(const f16x8*)(wb + ks * 32 + quad * 8);
    acc = __builtin_amdgcn_mfma_f32_16x16x32_f16(a, bb, acc, 0, 0, 0);
  }
  if (col < OUT_F) {
#pragma unroll
    for (int r = 0; r < 4; ++r) {
      const int t = wv * 16 + quad * 4 + r;
      if (t < tc)
        atomicAdd(&outcur[((size_t)(t0 + t) * BATCH + b) * OUT_F + col], acc[r]);
    }
  }
}

// ---------------------------------------------------------------------------
// LI readout scan + max. One thread per (b,o); 1 coalesced load per t,
// loads independent of scan state -> unroll lets them pipeline.
// ---------------------------------------------------------------------------
__global__ __launch_bounds__(128)
void li_scan(const float* __restrict__ outcur, float* __restrict__ out) {
  const int idx = blockIdx.x * 128 + threadIdx.x;
  if (idx >= BATCH * OUT_F) return;
  float vo = 0.f, io = 0.f, vmax = 0.f;
#pragma unroll 8
  for (int t = 0; t < T_STEPS; ++t) {
    const float oc = outcur[(size_t)t * (BATCH * OUT_F) + idx];
    const float von = DEC_V * vo + DT_V * io;
    io = DEC_I * io + oc;
    vo = von;
    vmax = fmaxf(vmax, von);
  }
  out[idx] = vmax;
}

__global__ void zero_state(float* __restrict__ p, int n) {
  int i = blockIdx.x * 256 + threadIdx.x;
  if (i < n) p[i] = 0.0f;
}

// ---------------------------------------------------------------------------
extern "C" void kernel_launch(void* const* d_in, const int* in_sizes, int n_in,
                              void* d_out, int out_size, void* d_ws, size_t ws_size,
                              hipStream_t stream) {
  const float* x  = (const float*)d_in[0];  // [T*B, 784]
  const float* w1 = (const float*)d_in[1];  // [2048, 784]
  const float* wo = (const float*)d_in[2];  // [10, 2048]
  float* out = (float*)d_out;               // [512, 10]

  const size_t BH = (size_t)BATCH * HID;
  const size_t WT_HALVES = (size_t)(HID / 16) * NKT * 512;

  // fixed: v1 | i1 | outcur[T,B,10] | WhT | WlT ; chunk: cur | AhT | AlT
  float* v1 = (float*)d_ws;
  float* i1 = v1 + BH;
  float* outcur = i1 + BH;
  _Float16* WhT = (_Float16*)(outcur + (size_t)T_STEPS * BATCH * OUT_F);
  _Float16* WlT = WhT + WT_HALVES;
  char* chunk0 = (char*)(WlT + WT_HALVES);

  const size_t base_bytes = (size_t)(chunk0 - (char*)d_ws);
  const size_t per_step = BH * 4 + (size_t)2 * 32 * NKT * 512 * 2;
  int Tc = T_STEPS;
  while (Tc > 1 && base_bytes + (size_t)Tc * per_step > ws_size) Tc >>= 1;

  float* cur = (float*)chunk0;
  _Float16* AhT = (_Float16*)(cur + (size_t)Tc * BH);
  _Float16* AlT = AhT + (size_t)Tc * 32 * NKT * 512;

  split_frag<<<HID / 16, 256, 0, stream>>>(w1, WhT, WlT);
  const int nzero = (int)(2 * BH) + T_STEPS * BATCH * OUT_F;
  zero_state<<<(nzero + 255) / 256, 256, 0, stream>>>(v1, nzero);

  for (int t0 = 0; t0 < T_STEPS; t0 += Tc) {
    const int tc = (T_STEPS - t0 < Tc) ? (T_STEPS - t0) : Tc;
    const int nrows = tc * BATCH;
    split_frag<<<nrows / 16, 256, 0, stream>>>(x + (size_t)t0 * BATCH * IN_F, AhT, AlT);
    dim3 grid(HID / 256, nrows / 128);
    gemm_fc1<<<grid, 256, 0, stream>>>(AhT, AlT, WhT, WlT, cur);
    dim3 lgrid(HID / 256, BATCH);
    lif_out<<<lgrid, 256, 0, stream>>>(cur, wo, v1, i1, outcur, tc, t0);
  }
  li_scan<<<(BATCH * OUT_F + 127) / 128, 128, 0, stream>>>(outcur, out);
}

// Round 9
// 628.542 us; speedup vs baseline: 1.1784x; 1.1784x over previous
//
#include <hip/hip_runtime.h>
#include <cstdint>
#include <cstddef>

#define T_STEPS 64
#define BATCH 512
#define IN_F 784
#define NKT 25          // k-tiles of 32 (784 padded to 800)
#define HID 2048
#define OUT_F 10

#define DEC_V 0.9f
#define DEC_I 0.8f
#define DT_V 0.1f
#define V_TH 0.5f

typedef __attribute__((ext_vector_type(8))) _Float16 f16x8;
typedef __attribute__((ext_vector_type(4))) float f32x4;

__device__ __forceinline__ void load_lds16h(const _Float16* g, _Float16* l) {
  __builtin_amdgcn_global_load_lds(
      (const __attribute__((address_space(1))) void*)g,
      (__attribute__((address_space(3))) void*)l, 16, 0, 0);
}

// ---------------------------------------------------------------------------
// Split fp32 [nrows,784] into f16 hi/lo in FRAGMENT-TILE order (R7-verified):
// tile (mt,kt) = 512 halves; lane l holds row (l&15), k-slice (l>>4)*8..+8.
// ---------------------------------------------------------------------------
__global__ __launch_bounds__(256)
void split_frag(const float* __restrict__ src, _Float16* __restrict__ hiT,
                _Float16* __restrict__ loT) {
  __shared__ float xr[16][804];
  const int mt = blockIdx.x;
  for (int i = threadIdx.x; i < 16 * IN_F; i += 256) {
    const int r = i / IN_F, c = i - r * IN_F;
    xr[r][c] = src[(size_t)(mt * 16 + r) * IN_F + c];
  }
  for (int i = threadIdx.x; i < 16 * 16; i += 256)
    xr[i >> 4][IN_F + (i & 15)] = 0.0f;
  __syncthreads();

  const int l = threadIdx.x & 63;
  const int g = threadIdx.x >> 6;
  const int r = l & 15, q = l >> 4;
  for (int kt = g; kt < NKT; kt += 4) {
    const float* s = &xr[r][kt * 32 + q * 8];
    f16x8 h, lo;
#pragma unroll
    for (int j = 0; j < 8; ++j) {
      const float v = s[j];
      const _Float16 hh = (_Float16)v;       // RTN
      h[j] = hh;
      lo[j] = (_Float16)(v - (float)hh);
    }
    const size_t off = ((size_t)mt * NKT + kt) * 512 + l * 8;
    *(f16x8*)&hiT[off] = h;
    *(f16x8*)&loT[off] = lo;
  }
}

// ---------------------------------------------------------------------------
// MFMA GEMM (R7-verified structure, 2 blocks/CU — 3 causes acc spills):
// C[m,n] = sum_k A[m,k]*W[n,k] via 3x f16-split products. Block 128x256,
// wave tile 64x128 (4x8 of 16x16x32): 96 MFMA : 24 conflict-free b128 reads.
// ---------------------------------------------------------------------------
__global__ __launch_bounds__(256, 2)
void gemm_fc1(const _Float16* __restrict__ AhT, const _Float16* __restrict__ AlT,
              const _Float16* __restrict__ WhT, const _Float16* __restrict__ WlT,
              float* __restrict__ C) {
  __shared__ _Float16 __attribute__((aligned(16))) sAh[8 * 512];
  __shared__ _Float16 __attribute__((aligned(16))) sAl[8 * 512];
  __shared__ _Float16 __attribute__((aligned(16))) sWh[16 * 512];
  __shared__ _Float16 __attribute__((aligned(16))) sWl[16 * 512];

  const int tid = threadIdx.x;
  const int lane = tid & 63;
  const int wv = tid >> 6;
  const int bmT = blockIdx.y * 8;
  const int bnT = blockIdx.x * 16;

  const int wrT = (wv >> 1) * 4;
  const int wcT = (wv & 1) * 8;
  const int col = lane & 15;
  const int quad = lane >> 4;

  f32x4 acc[4][8] = {};

  for (int kt = 0; kt < NKT; ++kt) {
    __syncthreads();
#pragma unroll
    for (int j = 0; j < 2; ++j) {
      const int t = wv * 2 + j;
      const size_t go = ((size_t)(bmT + t) * NKT + kt) * 512 + lane * 8;
      load_lds16h(AhT + go, sAh + t * 512);
      load_lds16h(AlT + go, sAl + t * 512);
    }
#pragma unroll
    for (int j = 0; j < 4; ++j) {
      const int t = wv * 4 + j;
      const size_t go = ((size_t)(bnT + t) * NKT + kt) * 512 + lane * 8;
      load_lds16h(WhT + go, sWh + t * 512);
      load_lds16h(WlT + go, sWl + t * 512);
    }
    __syncthreads();

    f16x8 fah[4], fal[4];
#pragma unroll
    for (int i = 0; i < 4; ++i) {
      fah[i] = *(const f16x8*)&sAh[(wrT + i) * 512 + lane * 8];
      fal[i] = *(const f16x8*)&sAl[(wrT + i) * 512 + lane * 8];
    }
#pragma unroll
    for (int ni = 0; ni < 8; ++ni) {
      const f16x8 fwh = *(const f16x8*)&sWh[(wcT + ni) * 512 + lane * 8];
      const f16x8 fwl = *(const f16x8*)&sWl[(wcT + ni) * 512 + lane * 8];
#pragma unroll
      for (int mi = 0; mi < 4; ++mi) {
        acc[mi][ni] = __builtin_amdgcn_mfma_f32_16x16x32_f16(fah[mi], fwh, acc[mi][ni], 0, 0, 0);
        acc[mi][ni] = __builtin_amdgcn_mfma_f32_16x16x32_f16(fah[mi], fwl, acc[mi][ni], 0, 0, 0);
        acc[mi][ni] = __builtin_amdgcn_mfma_f32_16x16x32_f16(fal[mi], fwh, acc[mi][ni], 0, 0, 0);
      }
    }
  }

  const int rowb = blockIdx.y * 128 + (wv >> 1) * 64;
  const int colb = blockIdx.x * 256 + (wv & 1) * 128;
#pragma unroll
  for (int mi = 0; mi < 4; ++mi)
#pragma unroll
    for (int ni = 0; ni < 8; ++ni)
#pragma unroll
      for (int r = 0; r < 4; ++r)
        C[(size_t)(rowb + mi * 16 + quad * 4 + r) * HID + colb + ni * 16 + col] =
            acc[mi][ni][r];
}

// ---------------------------------------------------------------------------
// Fused LIF scan + output projection; epilogue atomically accumulates the
// 8 h-chunk contributions into outcur[t][b][o] (~1 ulp order effects).
// ---------------------------------------------------------------------------
__global__ __launch_bounds__(256)
void lif_out(const float* __restrict__ cur, const float* __restrict__ wo,
             float* __restrict__ v1, float* __restrict__ i1,
             float* __restrict__ outcur, int tc, int t0) {
  __shared__ _Float16 zL[T_STEPS][264];
  __shared__ _Float16 wT[16][264];

  const int tid = threadIdx.x;
  const int hc = blockIdx.x;
  const int b = blockIdx.y;
  const int hb = hc * 256;

  for (int i = tid; i < 16 * 256; i += 256) {
    const int n = i >> 8, k = i & 255;
    wT[n][k] = (n < OUT_F) ? (_Float16)wo[(size_t)n * HID + hb + k] : (_Float16)0.f;
  }

  const int sidx = b * HID + hb + tid;
  float v = v1[sidx];
  float ci = i1[sidx];
#pragma unroll 4
  for (int t = 0; t < tc; ++t) {
    const float c = cur[(size_t)t * (BATCH * HID) + sidx];
    const float vd = DEC_V * v + DT_V * ci;
    const float z = (vd > V_TH) ? 1.0f : 0.0f;
    v = (1.0f - z) * vd;
    ci = DEC_I * ci + c;
    zL[t][tid] = (_Float16)z;
  }
  v1[sidx] = v;
  i1[sidx] = ci;
  __syncthreads();

  const int wv = tid >> 6;
  const int lane = tid & 63;
  const int col = lane & 15;
  const int quad = lane >> 4;
  f32x4 acc = {};
  const _Float16* za = &zL[wv * 16 + col][0];
  const _Float16* wb = &wT[col][0];
#pragma unroll
  for (int ks = 0; ks < 8; ++ks) {
    f16x8 a = *(const f16x8*)(za + ks * 32 + quad * 8);
    f16x8 bb = *(const f16x8*)(wb + ks * 32 + quad * 8);
    acc = __builtin_amdgcn_mfma_f32_16x16x32_f16(a, bb, acc, 0, 0, 0);
  }
  if (col < OUT_F) {
#pragma unroll
    for (int r = 0; r < 4; ++r) {
      const int t = wv * 16 + quad * 4 + r;
      if (t < tc)
        atomicAdd(&outcur[((size_t)(t0 + t) * BATCH + b) * OUT_F + col], acc[r]);
    }
  }
}

// ---------------------------------------------------------------------------
// LI readout scan + max. One thread per (b,o); coalesced, pipelined loads.
// ---------------------------------------------------------------------------
__global__ __launch_bounds__(128)
void li_scan(const float* __restrict__ outcur, float* __restrict__ out) {
  const int idx = blockIdx.x * 128 + threadIdx.x;
  if (idx >= BATCH * OUT_F) return;
  float vo = 0.f, io = 0.f, vmax = 0.f;
#pragma unroll 8
  for (int t = 0; t < T_STEPS; ++t) {
    const float oc = outcur[(size_t)t * (BATCH * OUT_F) + idx];
    const float von = DEC_V * vo + DT_V * io;
    io = DEC_I * io + oc;
    vo = von;
    vmax = fmaxf(vmax, von);
  }
  out[idx] = vmax;
}

__global__ void zero_state(float* __restrict__ p, int n) {
  int i = blockIdx.x * 256 + threadIdx.x;
  if (i < n) p[i] = 0.0f;
}

// ---------------------------------------------------------------------------
extern "C" void kernel_launch(void* const* d_in, const int* in_sizes, int n_in,
                              void* d_out, int out_size, void* d_ws, size_t ws_size,
                              hipStream_t stream) {
  const float* x  = (const float*)d_in[0];  // [T*B, 784]
  const float* w1 = (const float*)d_in[1];  // [2048, 784]
  const float* wo = (const float*)d_in[2];  // [10, 2048]
  float* out = (float*)d_out;               // [512, 10]

  const size_t BH = (size_t)BATCH * HID;
  const size_t WT_HALVES = (size_t)(HID / 16) * NKT * 512;

  // fixed: v1 | i1 | outcur[T,B,10] | WhT | WlT ; chunk: cur | AhT | AlT
  float* v1 = (float*)d_ws;
  float* i1 = v1 + BH;
  float* outcur = i1 + BH;
  _Float16* WhT = (_Float16*)(outcur + (size_t)T_STEPS * BATCH * OUT_F);
  _Float16* WlT = WhT + WT_HALVES;
  char* chunk0 = (char*)(WlT + WT_HALVES);

  const size_t base_bytes = (size_t)(chunk0 - (char*)d_ws);
  const size_t per_step = BH * 4 + (size_t)2 * 32 * NKT * 512 * 2;
  int Tc = T_STEPS;
  while (Tc > 1 && base_bytes + (size_t)Tc * per_step > ws_size) Tc >>= 1;
  if (Tc > 16) Tc = 16;   // keep cur chunk (67 MB) L3-resident for lif_out

  float* cur = (float*)chunk0;
  _Float16* AhT = (_Float16*)(cur + (size_t)Tc * BH);
  _Float16* AlT = AhT + (size_t)Tc * 32 * NKT * 512;

  split_frag<<<HID / 16, 256, 0, stream>>>(w1, WhT, WlT);
  const int nzero = (int)(2 * BH) + T_STEPS * BATCH * OUT_F;
  zero_state<<<(nzero + 255) / 256, 256, 0, stream>>>(v1, nzero);

  for (int t0 = 0; t0 < T_STEPS; t0 += Tc) {
    const int tc = (T_STEPS - t0 < Tc) ? (T_STEPS - t0) : Tc;
    const int nrows = tc * BATCH;
    split_frag<<<nrows / 16, 256, 0, stream>>>(x + (size_t)t0 * BATCH * IN_F, AhT, AlT);
    dim3 grid(HID / 256, nrows / 128);
    gemm_fc1<<<grid, 256, 0, stream>>>(AhT, AlT, WhT, WlT, cur);
    dim3 lgrid(HID / 256, BATCH);
    lif_out<<<lgrid, 256, 0, stream>>>(cur, wo, v1, i1, outcur, tc, t0);
  }
  li_scan<<<(BATCH * OUT_F + 127) / 128, 128, 0, stream>>>(outcur, out);
}